// Round 3
// baseline (778.013 us; speedup 1.0000x reference)
//
#include <hip/hip_runtime.h>
#include <hip/hip_bf16.h>

// Problem constants
#define B_    256
#define N_    2048
#define M_    128
#define VEC_  256
#define H_    1024
#define E_    512
#define P_    134
#define XDIM  384      // VEC + M
#define G4H   4096     // 4*H
#define PWC   524      // P + (P + 2M) = 134 + 390

typedef float  floatx4  __attribute__((ext_vector_type(4)));
typedef short  bf16x8   __attribute__((ext_vector_type(8)));
typedef unsigned short ushortx8 __attribute__((ext_vector_type(8)));
typedef unsigned short ushortx4 __attribute__((ext_vector_type(4)));

// ---- workspace layout: float region ----
#define OFF_GATES 0
#define OFF_H     (OFF_GATES + B_*G4H)
#define OFF_PW    (OFF_H     + B_*H_)
#define OFF_KR    (OFF_PW    + B_*PWC)
#define OFF_KW    (OFF_KR    + B_*M_)
#define OFF_E     (OFF_KW    + B_*M_)
#define OFF_A     (OFF_E     + B_*M_)
#define OFF_SCAL  (OFF_A     + B_*M_)
#define OFF_DOTR  (OFF_SCAL  + B_*16)
#define OFF_DOTW  (OFF_DOTR  + B_*N_)
#define OFF_MNORM (OFF_DOTW  + B_*N_)
#define OFF_WR    (OFF_MNORM + B_*N_)
#define OFF_WW    (OFF_WR    + B_*N_)
#define OFF_READ  (OFF_WW    + B_*N_)
#define FLOAT_TOTAL (OFF_READ + B_*M_)        // ~4.23M floats (~16.9 MB)
// ---- bf16 region (shorts), after float region ----
#define SOFF_X    0
#define SOFF_H    (SOFF_X   + B_*XDIM)        // 98,304
#define SOFF_WIH  (SOFF_H   + B_*H_)          // 360,448
#define SOFF_WHH  (SOFF_WIH + G4H*XDIM)       // 1,933,312
#define SHORT_TOTAL (SOFF_WHH + G4H*H_)       // 6,127,616 shorts (~12.3 MB)

__device__ __forceinline__ float bf2f(unsigned short u) {
    return __uint_as_float(((unsigned int)u) << 16);
}
__device__ __forceinline__ unsigned short f2bf(float f) {
    unsigned int x = __float_as_uint(f);
    x += 0x7fffu + ((x >> 16) & 1u);   // RTNE
    return (unsigned short)(x >> 16);
}
__device__ __forceinline__ float sigm(float x) { return 1.f / (1.f + expf(-x)); }
__device__ __forceinline__ float softplus_(float x) { return x > 20.f ? x : log1pf(expf(x)); }

// ---------------- K0: f32 -> bf16 conversion for the gates GEMM operands ----
__global__ __launch_bounds__(256) void k_cvt4(
    const float* __restrict__ s0, const float* __restrict__ s1,
    const float* __restrict__ s2, const float* __restrict__ s3,
    unsigned short* __restrict__ dst)  // segments at SOFF_*
{
    int i = (blockIdx.x * 256 + threadIdx.x) * 4;
    const float* s; int off;
    if      (i < SOFF_H)    { s = s0; off = SOFF_X; }
    else if (i < SOFF_WIH)  { s = s1; off = SOFF_H; }
    else if (i < SOFF_WHH)  { s = s2; off = SOFF_WIH; }
    else                    { s = s3; off = SOFF_WHH; }
    floatx4 v = *(const floatx4*)(s + (i - off));
    ushortx4 o;
    o[0] = f2bf(v[0]); o[1] = f2bf(v[1]); o[2] = f2bf(v[2]); o[3] = f2bf(v[3]);
    *(ushortx4*)(dst + i) = o;
}

// ---------------- K1: gates = [x|h_prev] @ [W_ih|W_hh]^T + b (bf16 MFMA) ----
__global__ __launch_bounds__(256) void k_gates(
    const unsigned short* __restrict__ wsb,     // bf16 region
    const float* __restrict__ b_ih, const float* __restrict__ b_hh,
    float* __restrict__ gates)                  // [256,4096]
{
    const unsigned short* x      = wsb + SOFF_X;
    const unsigned short* h_prev = wsb + SOFF_H;
    const unsigned short* W_ih   = wsb + SOFF_WIH;
    const unsigned short* W_hh   = wsb + SOFF_WHH;

    int gtid  = blockIdx.x * 256 + threadIdx.x;
    int wid   = gtid >> 6;              // 0..1023
    int lane  = threadIdx.x & 63;
    int tileM = wid >> 6;               // 0..15
    int nGrp  = wid & 63;               // 0..63
    int m0 = tileM << 4, n0 = nGrp << 6;
    int quad = lane >> 4, r16 = lane & 15;
    int koff = quad << 3;
    int mA = m0 + r16;

    floatx4 acc[4];
#pragma unroll
    for (int s = 0; s < 4; ++s) acc[s] = (floatx4){0.f, 0.f, 0.f, 0.f};

    const unsigned short* xrow = x + mA * XDIM;
    const unsigned short* hrow = h_prev + mA * H_;

#pragma unroll 2
    for (int kk = 0; kk < 12; ++kk) {            // K = 0..383 (x / W_ih)
        int k = (kk << 5) + koff;
        bf16x8 a  = *(const bf16x8*)(xrow + k);
        bf16x8 b0 = *(const bf16x8*)(W_ih + (n0 +  0 + r16) * XDIM + k);
        bf16x8 b1 = *(const bf16x8*)(W_ih + (n0 + 16 + r16) * XDIM + k);
        bf16x8 b2 = *(const bf16x8*)(W_ih + (n0 + 32 + r16) * XDIM + k);
        bf16x8 b3 = *(const bf16x8*)(W_ih + (n0 + 48 + r16) * XDIM + k);
        acc[0] = __builtin_amdgcn_mfma_f32_16x16x32_bf16(a, b0, acc[0], 0, 0, 0);
        acc[1] = __builtin_amdgcn_mfma_f32_16x16x32_bf16(a, b1, acc[1], 0, 0, 0);
        acc[2] = __builtin_amdgcn_mfma_f32_16x16x32_bf16(a, b2, acc[2], 0, 0, 0);
        acc[3] = __builtin_amdgcn_mfma_f32_16x16x32_bf16(a, b3, acc[3], 0, 0, 0);
    }
#pragma unroll 2
    for (int kk = 0; kk < 32; ++kk) {            // K = 384..1407 (h_prev / W_hh)
        int k = (kk << 5) + koff;
        bf16x8 a  = *(const bf16x8*)(hrow + k);
        bf16x8 b0 = *(const bf16x8*)(W_hh + (n0 +  0 + r16) * H_ + k);
        bf16x8 b1 = *(const bf16x8*)(W_hh + (n0 + 16 + r16) * H_ + k);
        bf16x8 b2 = *(const bf16x8*)(W_hh + (n0 + 32 + r16) * H_ + k);
        bf16x8 b3 = *(const bf16x8*)(W_hh + (n0 + 48 + r16) * H_ + k);
        acc[0] = __builtin_amdgcn_mfma_f32_16x16x32_bf16(a, b0, acc[0], 0, 0, 0);
        acc[1] = __builtin_amdgcn_mfma_f32_16x16x32_bf16(a, b1, acc[1], 0, 0, 0);
        acc[2] = __builtin_amdgcn_mfma_f32_16x16x32_bf16(a, b2, acc[2], 0, 0, 0);
        acc[3] = __builtin_amdgcn_mfma_f32_16x16x32_bf16(a, b3, acc[3], 0, 0, 0);
    }
    // C/D layout: col = lane&15, row = quad*4 + reg
#pragma unroll
    for (int s = 0; s < 4; ++s) {
        int n = n0 + (s << 4) + r16;
        float bias = b_ih[n] + b_hh[n];
#pragma unroll
        for (int r = 0; r < 4; ++r) {
            int m = m0 + (quad << 2) + r;
            gates[m * G4H + n] = acc[s][r] + bias;
        }
    }
}

// ---------------- K2: LSTM pointwise ----------------
__global__ __launch_bounds__(256) void k_lstm(
    const float* __restrict__ gates, const float* __restrict__ c_prev,
    float* __restrict__ h)
{
    int idx = blockIdx.x * 256 + threadIdx.x;   // 0..262143
    int b = idx >> 10, j = idx & 1023;
    const float* g = gates + b * G4H;
    float ig = sigm(g[j]);
    float fg = sigm(g[1024 + j]);
    float gg = tanhf(g[2048 + j]);
    float og = sigm(g[3072 + j]);
    float c  = fg * c_prev[idx] + ig * gg;
    h[idx] = og * tanhf(c);
}

// ---------------- K3: head params GEMM [256 x 524, K=1024], f32 ----------------
__global__ __launch_bounds__(256) void k_heads(
    const float* __restrict__ h,
    const float* __restrict__ W_r, const float* __restrict__ b_r,
    const float* __restrict__ W_w, const float* __restrict__ b_w,
    float* __restrict__ pw)                     // [256,524]
{
    __shared__ float hs[H_];
    int b = blockIdx.x, t = threadIdx.x;
    for (int i = t; i < H_; i += 256) hs[i] = h[b * H_ + i];
    __syncthreads();
    for (int c = t; c < PWC; c += 256) {
        const float* wrow;
        float bias;
        if (c < P_) { wrow = W_r + c * H_;             bias = b_r[c]; }
        else        { int j = c - P_; wrow = W_w + j * H_; bias = b_w[j]; }
        float acc = 0.f;
#pragma unroll 4
        for (int k = 0; k < H_; k += 4) {
            floatx4 wv = *(const floatx4*)(wrow + k);
            acc = fmaf(wv[0], hs[k], acc);
            acc = fmaf(wv[1], hs[k + 1], acc);
            acc = fmaf(wv[2], hs[k + 2], acc);
            acc = fmaf(wv[3], hs[k + 3], acc);
        }
        pw[b * PWC + c] = acc + bias;
    }
}

// ---------------- K4: head nonlinearities + norms, zero read acc ----------------
__global__ __launch_bounds__(128) void k_params(
    const float* __restrict__ pw,
    float* __restrict__ kr, float* __restrict__ kw,
    float* __restrict__ e,  float* __restrict__ a,
    float* __restrict__ scal, float* __restrict__ read_acc)
{
    int b = blockIdx.x, t = threadIdx.x;        // 128 threads
    const float* p = pw + b * PWC;
    float krv = tanhf(p[t]);
    float kwv = tanhf(p[P_ + t]);
    kr[b * M_ + t] = krv;
    kw[b * M_ + t] = kwv;
    e [b * M_ + t] = sigm (p[268 + t]);
    a [b * M_ + t] = tanhf(p[396 + t]);
    read_acc[b * M_ + t] = 0.f;

    float sr = krv * krv, sw = kwv * kwv;
#pragma unroll
    for (int m = 32; m; m >>= 1) { sr += __shfl_xor(sr, m); sw += __shfl_xor(sw, m); }
    __shared__ float red[4];
    if ((t & 63) == 0) { red[(t >> 6) * 2] = sr; red[(t >> 6) * 2 + 1] = sw; }
    __syncthreads();
    if (t == 0) {
        float nr = sqrtf(red[0] + red[2]);
        float nw = sqrtf(red[1] + red[3]);
        float* sc = scal + b * 16;
        // read head: beta@128 g@129 s@130..132 gamma@133
        {
            float beta = softplus_(p[128]);
            float g    = sigm(p[129]);
            float s0 = p[130], s1 = p[131], s2 = p[132];
            float mx = fmaxf(s0, fmaxf(s1, s2));
            float e0 = expf(s0 - mx), e1 = expf(s1 - mx), e2 = expf(s2 - mx);
            float es = e0 + e1 + e2;
            sc[0] = beta; sc[1] = g; sc[2] = e0 / es; sc[3] = e1 / es; sc[4] = e2 / es;
            sc[5] = 1.f + softplus_(p[133]); sc[6] = nr;
        }
        // write head: beta@262 g@263 s@264..266 gamma@267
        {
            float beta = softplus_(p[262]);
            float g    = sigm(p[263]);
            float s0 = p[264], s1 = p[265], s2 = p[266];
            float mx = fmaxf(s0, fmaxf(s1, s2));
            float e0 = expf(s0 - mx), e1 = expf(s1 - mx), e2 = expf(s2 - mx);
            float es = e0 + e1 + e2;
            sc[8] = beta; sc[9] = g; sc[10] = e0 / es; sc[11] = e1 / es; sc[12] = e2 / es;
            sc[13] = 1.f + softplus_(p[267]); sc[14] = nw;
        }
    }
}

// ---------------- K5: pass 1 over memory: dots + row norms (f32) ----------------
__global__ __launch_bounds__(256) void k_pass1(
    const float* __restrict__ memory,           // [256,2048,128] f32
    const float* __restrict__ kr, const float* __restrict__ kw,
    float* __restrict__ dotr, float* __restrict__ dotw, float* __restrict__ mnorm)
{
    int b = blockIdx.x >> 4;
    int chunk = blockIdx.x & 15;                // 128 rows per block
    __shared__ float krs[M_], kws[M_];
    int t = threadIdx.x;
    if (t < 128) krs[t] = kr[b * M_ + t];
    else         kws[t - 128] = kw[b * M_ + t - 128];
    __syncthreads();
    int wave = t >> 6, lane = t & 63;
    float k0r = krs[lane * 2], k1r = krs[lane * 2 + 1];
    float k0w = kws[lane * 2], k1w = kws[lane * 2 + 1];
    for (int i = 0; i < 32; ++i) {
        int n = chunk * 128 + wave * 32 + i;
        size_t ro = (size_t)b * N_ + n;
        float2 mv = *(const float2*)(memory + ro * M_ + lane * 2);
        float m0 = mv.x, m1 = mv.y;
        float dr = m0 * k0r + m1 * k1r;
        float dw = m0 * k0w + m1 * k1w;
        float ss = m0 * m0 + m1 * m1;
#pragma unroll
        for (int m = 32; m; m >>= 1) {
            dr += __shfl_xor(dr, m);
            dw += __shfl_xor(dw, m);
            ss += __shfl_xor(ss, m);
        }
        if (lane == 0) {
            dotr[ro] = dr; dotw[ro] = dw; mnorm[ro] = sqrtf(ss);
        }
    }
}

// ---------------- K6: addressing ----------------
__device__ __forceinline__ float blkSum(float v, float* red) {
#pragma unroll
    for (int m = 32; m; m >>= 1) v += __shfl_xor(v, m);
    int w = threadIdx.x >> 6;
    if ((threadIdx.x & 63) == 0) red[w] = v;
    __syncthreads();
    float r = red[0] + red[1] + red[2] + red[3];
    __syncthreads();
    return r;
}
__device__ __forceinline__ float blkMax(float v, float* red) {
#pragma unroll
    for (int m = 32; m; m >>= 1) v = fmaxf(v, __shfl_xor(v, m));
    int w = threadIdx.x >> 6;
    if ((threadIdx.x & 63) == 0) red[w] = v;
    __syncthreads();
    float r = fmaxf(fmaxf(red[0], red[1]), fmaxf(red[2], red[3]));
    __syncthreads();
    return r;
}

__global__ __launch_bounds__(256) void k_address(
    const float* __restrict__ dotr, const float* __restrict__ dotw,
    const float* __restrict__ mnorm,
    const float* __restrict__ prev_r, const float* __restrict__ prev_w,
    const float* __restrict__ scal,
    float* __restrict__ wr, float* __restrict__ ww)
{
    int b = blockIdx.x >> 1, head = blockIdx.x & 1;
    const float* dot = head ? dotw : dotr;
    const float* prev = head ? prev_w : prev_r;
    float* wout = head ? ww : wr;
    const float* sc = scal + b * 16 + head * 8;
    float beta = sc[0], g = sc[1], s0 = sc[2], s1 = sc[3], s2 = sc[4];
    float gamma = sc[5], kn = sc[6];

    __shared__ float buf[N_];
    __shared__ float red[4];
    int t = threadIdx.x;
    size_t base = (size_t)b * N_;

    float loc[8];
    float mx = -1e30f;
#pragma unroll
    for (int i = 0; i < 8; ++i) {
        int n = (i << 8) + t;
        float xv = beta * dot[base + n] / (mnorm[base + n] * kn + 1e-16f);
        loc[i] = xv;
        mx = fmaxf(mx, xv);
    }
    mx = blkMax(mx, red);
    float sum = 0.f;
#pragma unroll
    for (int i = 0; i < 8; ++i) { float ev = expf(loc[i] - mx); loc[i] = ev; sum += ev; }
    sum = blkSum(sum, red);
    float inv = 1.f / sum;
#pragma unroll
    for (int i = 0; i < 8; ++i) {
        int n = (i << 8) + t;
        float wc = loc[i] * inv;
        buf[n] = g * wc + (1.f - g) * prev[base + n];
    }
    __syncthreads();
    float psum = 0.f;
#pragma unroll
    for (int i = 0; i < 8; ++i) {
        int n = (i << 8) + t;
        float wt = s0 * buf[(n + N_ - 1) & (N_ - 1)] + s1 * buf[n] + s2 * buf[(n + 1) & (N_ - 1)];
        float wp = powf(wt, gamma);
        loc[i] = wp;
        psum += wp;
    }
    psum = blkSum(psum, red);
    float invp = 1.f / (psum + 1e-16f);
#pragma unroll
    for (int i = 0; i < 8; ++i) {
        int n = (i << 8) + t;
        wout[base + n] = loc[i] * invp;
    }
}

// ---------------- K7: memory update + read reduction (all f32) -----
__global__ __launch_bounds__(256) void k_update(
    const float* __restrict__ memory,
    const float* __restrict__ wr, const float* __restrict__ ww,
    const float* __restrict__ e, const float* __restrict__ a,
    float* __restrict__ read_acc,
    float* __restrict__ newmem)
{
    int b = blockIdx.x >> 6;
    int chunk = blockIdx.x & 63;                // 32 rows per block
    int t = threadIdx.x;
    __shared__ float es[M_], as_[M_];
    if (t < 128) es[t] = e[b * M_ + t];
    else         as_[t - 128] = a[b * M_ + t - 128];
    __syncthreads();

    int c = t & 15, r = t >> 4;
    int m8 = c << 3;
    float ev[8], av[8], racc[8];
#pragma unroll
    for (int j = 0; j < 8; ++j) { ev[j] = es[m8 + j]; av[j] = as_[m8 + j]; racc[j] = 0.f; }

#pragma unroll
    for (int stp = 0; stp < 2; ++stp) {
        int n = chunk * 32 + stp * 16 + r;
        size_t ro = (size_t)b * N_ + n;
        floatx4 mv0 = *(const floatx4*)(memory + ro * M_ + m8);
        floatx4 mv1 = *(const floatx4*)(memory + ro * M_ + m8 + 4);
        float wwv = ww[ro], wrv = wr[ro];
        floatx4 o0, o1;
#pragma unroll
        for (int j = 0; j < 4; ++j) {
            float mf = mv0[j];
            o0[j] = mf * (1.f - wwv * ev[j]) + wwv * av[j];
            racc[j] = fmaf(wrv, mf, racc[j]);
        }
#pragma unroll
        for (int j = 0; j < 4; ++j) {
            float mf = mv1[j];
            o1[j] = mf * (1.f - wwv * ev[4 + j]) + wwv * av[4 + j];
            racc[4 + j] = fmaf(wrv, mf, racc[4 + j]);
        }
        *(floatx4*)(newmem + ro * M_ + m8) = o0;
        *(floatx4*)(newmem + ro * M_ + m8 + 4) = o1;
    }

    __shared__ float rbuf[16][M_];
#pragma unroll
    for (int j = 0; j < 8; ++j) rbuf[r][m8 + j] = racc[j];
    __syncthreads();
    if (t < 128) {
        float s = 0.f;
#pragma unroll
        for (int rr = 0; rr < 16; ++rr) s += rbuf[rr][t];
        atomicAdd(read_acc + b * M_ + t, s);
    }
}

// ---------------- K8: output FC + sigmoid (f32 out) ----------------
__global__ __launch_bounds__(256) void k_out(
    const float* __restrict__ h, const float* __restrict__ read_acc,
    const float* __restrict__ W_fc, const float* __restrict__ b_fc,
    float* __restrict__ out)
{
    __shared__ float hc[H_ + M_];
    int b = blockIdx.x, t = threadIdx.x;
    for (int i = t; i < H_; i += 256) hc[i] = h[b * H_ + i];
    if (t < 128) hc[H_ + t] = read_acc[b * M_ + t];
    __syncthreads();
#pragma unroll
    for (int cc = 0; cc < 2; ++cc) {
        int c = cc * 256 + t;
        const float* wrow = W_fc + c * (H_ + M_);
        float acc = 0.f;
#pragma unroll 4
        for (int k = 0; k < H_ + M_; k += 4) {
            floatx4 wv = *(const floatx4*)(wrow + k);
            acc = fmaf(wv[0], hc[k], acc);
            acc = fmaf(wv[1], hc[k + 1], acc);
            acc = fmaf(wv[2], hc[k + 2], acc);
            acc = fmaf(wv[3], hc[k + 3], acc);
        }
        acc += b_fc[c];
        out[b * E_ + c] = sigm(acc);
    }
}

extern "C" void kernel_launch(void* const* d_in, const int* in_sizes, int n_in,
                              void* d_out, int out_size, void* d_ws, size_t ws_size,
                              hipStream_t stream)
{
    (void)in_sizes; (void)n_in; (void)out_size; (void)ws_size;
    const float* x      = (const float*)d_in[0];
    const float* memory = (const float*)d_in[1];
    const float* prev_r = (const float*)d_in[2];
    const float* prev_w = (const float*)d_in[3];
    const float* h_prev = (const float*)d_in[4];
    const float* c_prev = (const float*)d_in[5];
    const float* W_ih   = (const float*)d_in[6];
    const float* W_hh   = (const float*)d_in[7];
    const float* b_ih   = (const float*)d_in[8];
    const float* b_hh   = (const float*)d_in[9];
    const float* W_r    = (const float*)d_in[10];
    const float* b_r    = (const float*)d_in[11];
    const float* W_w    = (const float*)d_in[12];
    const float* b_w    = (const float*)d_in[13];
    const float* W_fc   = (const float*)d_in[14];
    const float* b_fc   = (const float*)d_in[15];

    float* ws = (float*)d_ws;
    float* gates = ws + OFF_GATES;
    float* h     = ws + OFF_H;
    float* pw    = ws + OFF_PW;
    float* kr    = ws + OFF_KR;
    float* kw    = ws + OFF_KW;
    float* e     = ws + OFF_E;
    float* a     = ws + OFF_A;
    float* scal  = ws + OFF_SCAL;
    float* dotr  = ws + OFF_DOTR;
    float* dotw  = ws + OFF_DOTW;
    float* mnorm = ws + OFF_MNORM;
    float* wrb   = ws + OFF_WR;
    float* wwb   = ws + OFF_WW;
    float* rd    = ws + OFF_READ;
    unsigned short* wsb = (unsigned short*)(ws + FLOAT_TOTAL);

    float* out    = (float*)d_out;
    float* newmem = out + B_ * E_;              // new_memory after out (f32)

    k_cvt4   <<<SHORT_TOTAL / 1024, 256, 0, stream>>>(x, h_prev, W_ih, W_hh, wsb);
    k_gates  <<<256,   256, 0, stream>>>(wsb, b_ih, b_hh, gates);
    k_lstm   <<<1024,  256, 0, stream>>>(gates, c_prev, h);
    k_heads  <<<256,   256, 0, stream>>>(h, W_r, b_r, W_w, b_w, pw);
    k_params <<<256,   128, 0, stream>>>(pw, kr, kw, e, a, scal, rd);
    k_pass1  <<<4096,  256, 0, stream>>>(memory, kr, kw, dotr, dotw, mnorm);
    k_address<<<512,   256, 0, stream>>>(dotr, dotw, mnorm, prev_r, prev_w, scal, wrb, wwb);
    k_update <<<16384, 256, 0, stream>>>(memory, wrb, wwb, e, a, rd, newmem);
    k_out    <<<256,   256, 0, stream>>>(h, rd, W_fc, b_fc, out);
}